// Round 1
// baseline (684.216 us; speedup 1.0000x reference)
//
#include <hip/hip_runtime.h>

#define CLS   160          // CLASS_NUM * NUM_PRED
#define TOPKN 1000
#define N0 147456
#define N1 36864
#define N2 9216
#define N3 2304
#define N4 576
#define NROWS (N0 + N1 + N2 + N3)   // 195840 anchors needing top-k keys
#define BD1 N0
#define BD2 (N0 + N1)
#define BD3 (N0 + N1 + N2)
#define NSEL (4 * TOPKN + N4)       // 4576 selected anchors
#define NBINS 65536
#define CAND_CAP 2048

__device__ __forceinline__ unsigned sortable(float f) {
    unsigned u = __float_as_uint(f);
    return (u & 0x80000000u) ? ~u : (u | 0x80000000u);
}

// ---------------------------------------------------------------------------
// K1: one wave per anchor row: ruler = max over 160 cls values -> sortable key.
// Fused 16-bit-prefix histogram (per level) via global atomics (lane 0 only).
// ---------------------------------------------------------------------------
__global__ __launch_bounds__(256) void k_ruler(
    const float* __restrict__ c0, const float* __restrict__ c1,
    const float* __restrict__ c2, const float* __restrict__ c3,
    unsigned* __restrict__ keys, unsigned* __restrict__ hist)
{
    int w    = (blockIdx.x * 256 + threadIdx.x) >> 6;
    int lane = threadIdx.x & 63;
    if (w >= NROWS) return;
    const float* cp;
    int level;
    if (w < BD1)      { cp = c0 + (size_t)w * CLS;         level = 0; }
    else if (w < BD2) { cp = c1 + (size_t)(w - BD1) * CLS; level = 1; }
    else if (w < BD3) { cp = c2 + (size_t)(w - BD2) * CLS; level = 2; }
    else              { cp = c3 + (size_t)(w - BD3) * CLS; level = 3; }

    float m = fmaxf(cp[lane], cp[lane + 64]);
    if (lane < 32) m = fmaxf(m, cp[lane + 128]);
    #pragma unroll
    for (int o = 32; o > 0; o >>= 1) m = fmaxf(m, __shfl_xor(m, o));

    if (lane == 0) {
        unsigned key = sortable(m);
        keys[w] = key;
        atomicAdd(&hist[level * NBINS + (key >> 16)], 1u);
    }
}

// ---------------------------------------------------------------------------
// K2: per level (4 blocks), scan histogram descending to find the bin holding
// the 1000th-largest key. Threshold = lower edge of that bin. Also zero the
// candidate counter for this call.
// ---------------------------------------------------------------------------
__global__ __launch_bounds__(1024) void k_decide(const unsigned* __restrict__ hist,
                                                 unsigned* __restrict__ ctrl)
{
    int level = blockIdx.x;
    const unsigned* h = hist + level * NBINS;
    int t = threadIdx.x;
    __shared__ unsigned s[1024];

    unsigned sum = 0;
    #pragma unroll 4
    for (int i = 0; i < 64; ++i) sum += h[t * 64 + i];
    s[t] = sum;
    __syncthreads();

    // suffix sums: s[t] = sum over chunks t..1023 (Hillis-Steele)
    for (int off = 1; off < 1024; off <<= 1) {
        unsigned v   = s[t];
        unsigned add = (t + off < 1024) ? s[t + off] : 0u;
        __syncthreads();
        s[t] = v + add;
        __syncthreads();
    }

    // exactly one thread has suf[t] >= K and suf[t+1] < K (suf nonincreasing)
    if (s[t] >= TOPKN && (t == 1023 || s[t + 1] < TOPKN)) {
        unsigned cum = (t == 1023) ? 0u : s[t + 1];
        int edge = t * 64;
        for (int b = t * 64 + 63; b >= t * 64; --b) {
            cum += h[b];
            if (cum >= TOPKN) { edge = b; break; }
        }
        ctrl[level]     = ((unsigned)edge) << 16;  // threshold key
        ctrl[4 + level] = 0u;                      // reset candidate counter
    }
}

// ---------------------------------------------------------------------------
// K3: compact all (key, local_idx) with key >= threshold into per-level buffer.
// ---------------------------------------------------------------------------
__global__ __launch_bounds__(256) void k_compact(const unsigned* __restrict__ keys,
                                                 unsigned* __restrict__ ctrl,
                                                 uint2* __restrict__ cand)
{
    int w = blockIdx.x * 256 + threadIdx.x;
    if (w >= NROWS) return;
    int level, base;
    if (w < BD1)      { level = 0; base = 0;   }
    else if (w < BD2) { level = 1; base = BD1; }
    else if (w < BD3) { level = 2; base = BD2; }
    else              { level = 3; base = BD3; }
    unsigned key = keys[w];
    if (key >= ctrl[level]) {
        unsigned pos = atomicAdd(&ctrl[4 + level], 1u);
        if (pos < CAND_CAP)
            cand[level * CAND_CAP + pos] = make_uint2(key, (unsigned)(w - base));
    }
}

// ---------------------------------------------------------------------------
// K4: exact stable top-k order. Composite = (key << 32) | ~idx, rank by
// brute-force comparison (C ~= 1100 candidates). Descending by key, ties by
// ascending index — exactly lax.top_k semantics.
// ---------------------------------------------------------------------------
__global__ __launch_bounds__(1024) void k_rank(const uint2* __restrict__ cand,
                                               const unsigned* __restrict__ ctrl,
                                               unsigned* __restrict__ sel)
{
    int level = blockIdx.x;
    unsigned cnt = ctrl[4 + level];
    if (cnt > CAND_CAP) cnt = CAND_CAP;
    __shared__ unsigned long long a[CAND_CAP];
    for (int i = threadIdx.x; i < (int)cnt; i += 1024) {
        uint2 c = cand[level * CAND_CAP + i];
        a[i] = ((unsigned long long)c.x << 32) | (unsigned)(~c.y);
    }
    __syncthreads();
    for (int i = threadIdx.x; i < (int)cnt; i += 1024) {
        unsigned long long mine = a[i];
        unsigned rank = 0;
        for (int j = 0; j < (int)cnt; ++j) rank += (a[j] > mine) ? 1u : 0u;
        if (rank < TOPKN)
            sel[level * TOPKN + rank] = ~(unsigned)(mine & 0xFFFFFFFFull);
    }
}

// ---------------------------------------------------------------------------
// K5: one block per selected anchor. Gather cls row -> sigmoid in LDS, decode
// both bboxes, emit 80 rows x 12 floats as 240 coalesced float4 stores.
// Row layout: [b0(4), score0, tag, b1(4), score1, tag]
// ---------------------------------------------------------------------------
__global__ __launch_bounds__(256) void k_epilogue(
    const float* a0, const float* a1, const float* a2, const float* a3, const float* a4,
    const float* c0, const float* c1, const float* c2, const float* c3, const float* c4,
    const float* r0, const float* r1, const float* r2, const float* r3, const float* r4,
    const unsigned* __restrict__ sel, float* __restrict__ out)
{
    int s = blockIdx.x;
    int level, idx;
    if (s < 4 * TOPKN) {
        level = s / TOPKN;
        idx   = (int)sel[s];          // sel laid out level*1000 + rank == s
    } else {
        level = 4;
        idx   = s - 4 * TOPKN;
    }
    const float *A, *C, *R;
    switch (level) {
        case 0: A = a0; C = c0; R = r0; break;
        case 1: A = a1; C = c1; R = r1; break;
        case 2: A = a2; C = c2; R = r2; break;
        case 3: A = a3; C = c3; R = r3; break;
        default: A = a4; C = c4; R = r4; break;
    }

    __shared__ float sc[CLS];
    __shared__ float bb[8];

    const float* cp = C + (size_t)idx * CLS;
    if (threadIdx.x < CLS) {
        float x = cp[threadIdx.x];
        sc[threadIdx.x] = 1.0f / (1.0f + __expf(-x));
    }
    if (threadIdx.x == 192) {   // wave 3, not used by the cls gather
        const float* ap = A + (size_t)idx * 4;
        const float* rp = R + (size_t)idx * 8;
        float x1 = ap[0], y1 = ap[1], x2 = ap[2], y2 = ap[3];
        float w  = x2 - x1 + 1.0f, h = y2 - y1 + 1.0f;
        float cx = x1 + 0.5f * w,  cy = y1 + 0.5f * h;
        #pragma unroll
        for (int p = 0; p < 2; ++p) {
            float pcx = cx + rp[4 * p + 0] * w;
            float pcy = cy + rp[4 * p + 1] * h;
            float pw  = w * __expf(rp[4 * p + 2]);
            float ph  = h * __expf(rp[4 * p + 3]);
            bb[4 * p + 0] = pcx - 0.5f * pw;
            bb[4 * p + 1] = pcy - 0.5f * ph;
            bb[4 * p + 2] = pcx + 0.5f * pw;
            bb[4 * p + 3] = pcy + 0.5f * ph;
        }
    }
    __syncthreads();

    float4* orow = (float4*)(out + (size_t)s * 960);   // 80 * 12 floats
    if (threadIdx.x < 240) {
        int j = threadIdx.x / 3, part = threadIdx.x % 3;
        float tag = (float)(j + 1);
        float4 v;
        if (part == 0)      v = make_float4(bb[0], bb[1], bb[2], bb[3]);
        else if (part == 1) v = make_float4(sc[j], tag, bb[4], bb[5]);
        else                v = make_float4(bb[6], bb[7], sc[80 + j], tag);
        orow[threadIdx.x] = v;
    }
}

// ---------------------------------------------------------------------------
// Workspace layout (uint32 words):
//   keys[NROWS] | hist[4*NBINS] | ctrl[8] (thr[4], cnt[4]) |
//   cand[4*CAND_CAP] (uint2)    | sel[4*TOPKN]
// Total ~1.9 MB.
// ---------------------------------------------------------------------------
extern "C" void kernel_launch(void* const* d_in, const int* in_sizes, int n_in,
                              void* d_out, int out_size, void* d_ws, size_t ws_size,
                              hipStream_t stream)
{
    // setup_inputs() dict order is interleaved (anchors0, cls0, reg0, anchors1, ...)
    // Detect defensively: interleaved => in_sizes[1] == 147456*160 (cls0);
    // grouped => in_sizes[1] == 36864*4 (anchors1).
    bool interleaved = (in_sizes[1] > 1000000);
    const float *A[5], *C[5], *R[5];
    for (int i = 0; i < 5; ++i) {
        if (interleaved) {
            A[i] = (const float*)d_in[3 * i + 0];
            C[i] = (const float*)d_in[3 * i + 1];
            R[i] = (const float*)d_in[3 * i + 2];
        } else {
            A[i] = (const float*)d_in[i];
            C[i] = (const float*)d_in[5 + i];
            R[i] = (const float*)d_in[10 + i];
        }
    }

    unsigned* keys = (unsigned*)d_ws;
    unsigned* hist = keys + NROWS;
    unsigned* ctrl = hist + 4 * NBINS;
    uint2*    cand = (uint2*)(ctrl + 8);
    unsigned* sel  = (unsigned*)(cand + 4 * CAND_CAP);

    hipMemsetAsync(hist, 0, 4 * NBINS * sizeof(unsigned), stream);

    int rblocks = (NROWS * 64) / 256;   // exact: 48960
    k_ruler<<<rblocks, 256, 0, stream>>>(C[0], C[1], C[2], C[3], keys, hist);
    k_decide<<<4, 1024, 0, stream>>>(hist, ctrl);
    k_compact<<<(NROWS + 255) / 256, 256, 0, stream>>>(keys, ctrl, cand);
    k_rank<<<4, 1024, 0, stream>>>(cand, ctrl, sel);
    k_epilogue<<<NSEL, 256, 0, stream>>>(A[0], A[1], A[2], A[3], A[4],
                                         C[0], C[1], C[2], C[3], C[4],
                                         R[0], R[1], R[2], R[3], R[4],
                                         sel, (float*)d_out);
}

// Round 2
// 140.278 us; speedup vs baseline: 4.8776x; 4.8776x over previous
//
#include <hip/hip_runtime.h>

#define CLS   160          // CLASS_NUM * NUM_PRED
#define TOPKN 1000
#define N0 147456
#define N1 36864
#define N2 9216
#define N3 2304
#define N4 576
#define NROWS (N0 + N1 + N2 + N3)   // 195840 anchors needing top-k keys
#define BD1 N0
#define BD2 (N0 + N1)
#define BD3 (N0 + N1 + N2)
#define NSEL (4 * TOPKN + N4)       // 4576 selected anchors
#define NBINS 65536
#define CAND_CAP 2048

__device__ __forceinline__ unsigned sortable(float f) {
    unsigned u = __float_as_uint(f);
    return (u & 0x80000000u) ? ~u : (u | 0x80000000u);
}

// ---------------------------------------------------------------------------
// K1: ruler keys only, NO atomics. 8 lanes per row, 5 float4 loads per lane
// (one vector-load instruction covers 8 complete rows). 3-step shuffle
// reduce within each 8-lane group. Grid-stride over row-groups of 8.
// 1530 blocks * 4 waves = 6120 waves; 24480 groups -> exactly 4 groups/wave.
// ---------------------------------------------------------------------------
__global__ __launch_bounds__(256) void k_ruler(
    const float* __restrict__ c0, const float* __restrict__ c1,
    const float* __restrict__ c2, const float* __restrict__ c3,
    unsigned* __restrict__ keys)
{
    int tid  = blockIdx.x * 256 + threadIdx.x;
    int wv   = tid >> 6;
    int lane = tid & 63;
    int sub  = lane >> 3;   // row within group of 8
    int col  = lane & 7;    // float4 column group
    const int NW = 1530 * 4;
    for (int g = wv; g < NROWS / 8; g += NW) {
        int r0 = g * 8;     // 8 rows, always within one level (sizes % 8 == 0)
        const float* cb; int lr;
        if (r0 < BD1)      { cb = c0; lr = r0; }
        else if (r0 < BD2) { cb = c1; lr = r0 - BD1; }
        else if (r0 < BD3) { cb = c2; lr = r0 - BD2; }
        else               { cb = c3; lr = r0 - BD3; }
        const float4* p = (const float4*)cb + (size_t)(lr + sub) * 40 + col;
        float m = -3.4e38f;
        #pragma unroll
        for (int k = 0; k < 5; ++k) {
            float4 v = p[8 * k];
            m = fmaxf(m, fmaxf(fmaxf(v.x, v.y), fmaxf(v.z, v.w)));
        }
        m = fmaxf(m, __shfl_xor(m, 1));
        m = fmaxf(m, __shfl_xor(m, 2));
        m = fmaxf(m, __shfl_xor(m, 4));
        if (col == 0) keys[r0 + sub] = sortable(m);
    }
}

// ---------------------------------------------------------------------------
// K2: histogram from keys (L2-resident, 783 KB). Block = (level, 4096-bin
// segment, 1/4 chunk of the level). LDS counts; flush only nonzero bins with
// non-contended global atomicAdd (each address touched by <= 4 blocks).
// ---------------------------------------------------------------------------
__global__ __launch_bounds__(256) void k_hist(const unsigned* __restrict__ keys,
                                              unsigned* __restrict__ hist)
{
    int b     = blockIdx.x;
    int level = b >> 6;          // 64 blocks per level
    int seg   = (b >> 2) & 15;   // 4096-bin segment
    int chunk = b & 3;           // quarter of the level's rows
    __shared__ unsigned cnt[4096];
    for (int i = threadIdx.x; i < 4096; i += 256) cnt[i] = 0;
    __syncthreads();
    int base, n;
    switch (level) {
        case 0:  base = 0;   n = N0; break;
        case 1:  base = BD1; n = N1; break;
        case 2:  base = BD2; n = N2; break;
        default: base = BD3; n = N3; break;
    }
    const unsigned* kp = keys + base;
    unsigned lo = (unsigned)seg << 12;
    int q = n >> 2;                         // all level sizes % 4 == 0
    int i1 = chunk * q + q;
    for (int i = chunk * q + threadIdx.x; i < i1; i += 256) {
        unsigned bin = kp[i] >> 16;
        if ((bin >> 12) == (unsigned)seg) atomicAdd(&cnt[bin - lo], 1u);
    }
    __syncthreads();
    unsigned* h = hist + level * NBINS + lo;
    for (int i = threadIdx.x; i < 4096; i += 256) {
        unsigned c = cnt[i];
        if (c) atomicAdd(&h[i], c);
    }
}

// ---------------------------------------------------------------------------
// K3: per level (4 blocks), scan histogram descending to find the bin holding
// the 1000th-largest key. Threshold = lower edge of that bin. Also zero the
// candidate counter for this call.
// ---------------------------------------------------------------------------
__global__ __launch_bounds__(1024) void k_decide(const unsigned* __restrict__ hist,
                                                 unsigned* __restrict__ ctrl)
{
    int level = blockIdx.x;
    const unsigned* h = hist + level * NBINS;
    int t = threadIdx.x;
    __shared__ unsigned s[1024];

    unsigned sum = 0;
    #pragma unroll 4
    for (int i = 0; i < 64; ++i) sum += h[t * 64 + i];
    s[t] = sum;
    __syncthreads();

    // suffix sums: s[t] = sum over chunks t..1023 (Hillis-Steele)
    for (int off = 1; off < 1024; off <<= 1) {
        unsigned v   = s[t];
        unsigned add = (t + off < 1024) ? s[t + off] : 0u;
        __syncthreads();
        s[t] = v + add;
        __syncthreads();
    }

    // exactly one thread has suf[t] >= K and suf[t+1] < K (suf nonincreasing)
    if (s[t] >= TOPKN && (t == 1023 || s[t + 1] < TOPKN)) {
        unsigned cum = (t == 1023) ? 0u : s[t + 1];
        int edge = t * 64;
        for (int b = t * 64 + 63; b >= t * 64; --b) {
            cum += h[b];
            if (cum >= TOPKN) { edge = b; break; }
        }
        ctrl[level]     = ((unsigned)edge) << 16;  // threshold key
        ctrl[4 + level] = 0u;                      // reset candidate counter
    }
}

// ---------------------------------------------------------------------------
// K4: compact (key, local_idx) with key >= threshold. Wave-aggregated
// counter atomic: one atomicAdd per wave with >=1 candidate. Level
// boundaries are all multiples of 64, so a wave never straddles levels.
// ---------------------------------------------------------------------------
__global__ __launch_bounds__(256) void k_compact(const unsigned* __restrict__ keys,
                                                 unsigned* __restrict__ ctrl,
                                                 uint2* __restrict__ cand)
{
    int w = blockIdx.x * 256 + threadIdx.x;
    int lane = threadIdx.x & 63;
    int level, base;
    if (w < BD1)      { level = 0; base = 0;   }
    else if (w < BD2) { level = 1; base = BD1; }
    else if (w < BD3) { level = 2; base = BD2; }
    else              { level = 3; base = BD3; }
    unsigned key = keys[w];
    bool pass = key >= ctrl[level];
    unsigned long long mask = __ballot(pass);
    if (pass) {
        int leader    = __ffsll((long long)mask) - 1;
        unsigned tot  = (unsigned)__popcll(mask);
        unsigned rank = (unsigned)__popcll(mask & ((1ull << lane) - 1ull));
        unsigned bpos = 0;
        if (lane == leader) bpos = atomicAdd(&ctrl[4 + level], tot);
        bpos = (unsigned)__shfl((int)bpos, leader);
        unsigned pos = bpos + rank;
        if (pos < CAND_CAP)
            cand[level * CAND_CAP + pos] = make_uint2(key, (unsigned)(w - base));
    }
}

// ---------------------------------------------------------------------------
// K5: exact stable top-k order. Composite = (key << 32) | ~idx, rank by
// brute-force comparison (C ~= 1100 candidates). Descending by key, ties by
// ascending index — exactly lax.top_k semantics.
// ---------------------------------------------------------------------------
__global__ __launch_bounds__(1024) void k_rank(const uint2* __restrict__ cand,
                                               const unsigned* __restrict__ ctrl,
                                               unsigned* __restrict__ sel)
{
    int level = blockIdx.x;
    unsigned cnt = ctrl[4 + level];
    if (cnt > CAND_CAP) cnt = CAND_CAP;
    __shared__ unsigned long long a[CAND_CAP];
    for (int i = threadIdx.x; i < (int)cnt; i += 1024) {
        uint2 c = cand[level * CAND_CAP + i];
        a[i] = ((unsigned long long)c.x << 32) | (unsigned)(~c.y);
    }
    __syncthreads();
    for (int i = threadIdx.x; i < (int)cnt; i += 1024) {
        unsigned long long mine = a[i];
        unsigned rank = 0;
        for (int j = 0; j < (int)cnt; ++j) rank += (a[j] > mine) ? 1u : 0u;
        if (rank < TOPKN)
            sel[level * TOPKN + rank] = ~(unsigned)(mine & 0xFFFFFFFFull);
    }
}

// ---------------------------------------------------------------------------
// K6: one block per selected anchor. Gather cls row -> sigmoid in LDS, decode
// both bboxes, emit 80 rows x 12 floats as 240 coalesced float4 stores.
// Row layout: [b0(4), score0, tag, b1(4), score1, tag]
// ---------------------------------------------------------------------------
__global__ __launch_bounds__(256) void k_epilogue(
    const float* a0, const float* a1, const float* a2, const float* a3, const float* a4,
    const float* c0, const float* c1, const float* c2, const float* c3, const float* c4,
    const float* r0, const float* r1, const float* r2, const float* r3, const float* r4,
    const unsigned* __restrict__ sel, float* __restrict__ out)
{
    int s = blockIdx.x;
    int level, idx;
    if (s < 4 * TOPKN) {
        level = s / TOPKN;
        idx   = (int)sel[s];          // sel laid out level*1000 + rank == s
    } else {
        level = 4;
        idx   = s - 4 * TOPKN;
    }
    const float *A, *C, *R;
    switch (level) {
        case 0: A = a0; C = c0; R = r0; break;
        case 1: A = a1; C = c1; R = r1; break;
        case 2: A = a2; C = c2; R = r2; break;
        case 3: A = a3; C = c3; R = r3; break;
        default: A = a4; C = c4; R = r4; break;
    }

    __shared__ float sc[CLS];
    __shared__ float bb[8];

    const float* cp = C + (size_t)idx * CLS;
    if (threadIdx.x < CLS) {
        float x = cp[threadIdx.x];
        sc[threadIdx.x] = 1.0f / (1.0f + __expf(-x));
    }
    if (threadIdx.x == 192) {   // wave 3, not used by the cls gather
        const float* ap = A + (size_t)idx * 4;
        const float* rp = R + (size_t)idx * 8;
        float x1 = ap[0], y1 = ap[1], x2 = ap[2], y2 = ap[3];
        float w  = x2 - x1 + 1.0f, h = y2 - y1 + 1.0f;
        float cx = x1 + 0.5f * w,  cy = y1 + 0.5f * h;
        #pragma unroll
        for (int p = 0; p < 2; ++p) {
            float pcx = cx + rp[4 * p + 0] * w;
            float pcy = cy + rp[4 * p + 1] * h;
            float pw  = w * __expf(rp[4 * p + 2]);
            float ph  = h * __expf(rp[4 * p + 3]);
            bb[4 * p + 0] = pcx - 0.5f * pw;
            bb[4 * p + 1] = pcy - 0.5f * ph;
            bb[4 * p + 2] = pcx + 0.5f * pw;
            bb[4 * p + 3] = pcy + 0.5f * ph;
        }
    }
    __syncthreads();

    float4* orow = (float4*)(out + (size_t)s * 960);   // 80 * 12 floats
    if (threadIdx.x < 240) {
        int j = threadIdx.x / 3, part = threadIdx.x % 3;
        float tag = (float)(j + 1);
        float4 v;
        if (part == 0)      v = make_float4(bb[0], bb[1], bb[2], bb[3]);
        else if (part == 1) v = make_float4(sc[j], tag, bb[4], bb[5]);
        else                v = make_float4(bb[6], bb[7], sc[80 + j], tag);
        orow[threadIdx.x] = v;
    }
}

// ---------------------------------------------------------------------------
// Workspace layout (uint32 words):
//   keys[NROWS] | hist[4*NBINS] | ctrl[8] (thr[4], cnt[4]) |
//   cand[4*CAND_CAP] (uint2)    | sel[4*TOPKN]
// Total ~1.9 MB.
// ---------------------------------------------------------------------------
extern "C" void kernel_launch(void* const* d_in, const int* in_sizes, int n_in,
                              void* d_out, int out_size, void* d_ws, size_t ws_size,
                              hipStream_t stream)
{
    bool interleaved = (in_sizes[1] > 1000000);
    const float *A[5], *C[5], *R[5];
    for (int i = 0; i < 5; ++i) {
        if (interleaved) {
            A[i] = (const float*)d_in[3 * i + 0];
            C[i] = (const float*)d_in[3 * i + 1];
            R[i] = (const float*)d_in[3 * i + 2];
        } else {
            A[i] = (const float*)d_in[i];
            C[i] = (const float*)d_in[5 + i];
            R[i] = (const float*)d_in[10 + i];
        }
    }

    unsigned* keys = (unsigned*)d_ws;
    unsigned* hist = keys + NROWS;
    unsigned* ctrl = hist + 4 * NBINS;
    uint2*    cand = (uint2*)(ctrl + 8);
    unsigned* sel  = (unsigned*)(cand + 4 * CAND_CAP);

    hipMemsetAsync(hist, 0, 4 * NBINS * sizeof(unsigned), stream);

    k_ruler<<<1530, 256, 0, stream>>>(C[0], C[1], C[2], C[3], keys);
    k_hist<<<256, 256, 0, stream>>>(keys, hist);
    k_decide<<<4, 1024, 0, stream>>>(hist, ctrl);
    k_compact<<<NROWS / 256, 256, 0, stream>>>(keys, ctrl, cand);
    k_rank<<<4, 1024, 0, stream>>>(cand, ctrl, sel);
    k_epilogue<<<NSEL, 256, 0, stream>>>(A[0], A[1], A[2], A[3], A[4],
                                         C[0], C[1], C[2], C[3], C[4],
                                         R[0], R[1], R[2], R[3], R[4],
                                         sel, (float*)d_out);
}